// Round 5
// baseline (223.264 us; speedup 1.0000x reference)
//
#include <hip/hip_runtime.h>

typedef _Float16 f16;
typedef _Float16 f16x2 __attribute__((ext_vector_type(2)));
typedef _Float16 f16x4 __attribute__((ext_vector_type(4)));
typedef _Float16 f16x8 __attribute__((ext_vector_type(8)));
typedef float    f32x4 __attribute__((ext_vector_type(4)));

// Geometry:
//   x:   (4,128,64,64) f32     p5: (128,21,64,64) f32
//   p6:  (128,21,128)  f32     out:(4,128,64,64)  f32
// Workspace:
//   xk  [3][4][128][82][64] f16 = x*(1/8), w-inner (for gram)
//   xkT [3][4][82][64][128] f16 = x*(1/8), c-inner (for outp A-fragments)
//   p5T [21][64][64][128]   f16 = p5, c-inner
//   t6T [4][128][2688]      f16 = p6 * t3, d-major
//   t3p [8][4][21][128][128] f16 = split-K Gram partials   (aliased by t8p)
//   t8p [4][4][64][128][64]  f16 = split-K out partials
#define XROWS 82
#define XSTR  (XROWS * 64)
#define XK_ELEMS  (3u * 4u * 128u * (unsigned)XSTR)
static const size_t XKT_OFF   = (size_t)XK_ELEMS * 2;                 // 16.12 MB
static const size_t XKT_BYTES = (size_t)3 * 4 * 82 * 64 * 128 * 2;    // 16.12 MB
static const size_t P5T_OFF   = XKT_OFF + XKT_BYTES;
static const size_t P5T_BYTES = (size_t)21 * 64 * 64 * 128 * 2;       // 22.0 MB
static const size_t T6T_OFF   = P5T_OFF + P5T_BYTES;
static const size_t T6T_BYTES = (size_t)4 * 128 * 2688 * 2;           // 2.75 MB
static const size_t T3P_OFF   = T6T_OFF + T6T_BYTES;
static const size_t T8P_OFF   = T3P_OFF;   // t3p dead before outp writes t8p

__device__ __forceinline__ void gl16(const f16* g, f16* l) {
  __builtin_amdgcn_global_load_lds((const __attribute__((address_space(1))) void*)g,
                                   (__attribute__((address_space(3))) void*)l, 16, 0, 0);
}

// ---------------------------------------------------------------- prep (xk, w-inner)
__global__ __launch_bounds__(256) void prep_kernel(const float* __restrict__ x,
                                                   f16* __restrict__ xk) {
  unsigned p = blockIdx.x * 256u + threadIdx.x;
  unsigned total = 3u * 4u * 128u * 82u * 32u;
  if (p >= total) return;
  unsigned wp   = p & 31u;
  unsigned row  = (p >> 5) % 82u;
  unsigned rest = p / (32u * 82u);
  unsigned c    = rest & 127u;
  unsigned rest2 = rest >> 7;
  unsigned n    = rest2 & 3u;
  unsigned kc   = rest2 >> 2;
  int hsrc = (int)row - 9;
  int wsrc = (int)(wp * 2u) + 2 * (int)kc - 2;
  f16x2 v; v.x = (f16)0.f; v.y = (f16)0.f;
  if (hsrc >= 0 && hsrc < 64 && wsrc >= 0 && wsrc < 64) {
    const float2* src = (const float2*)(x + (((size_t)(n * 128u + c) * 64u + (unsigned)hsrc) * 64u + (unsigned)wsrc));
    float2 xv = *src;
    v.x = (f16)(xv.x * 0.125f);
    v.y = (f16)(xv.y * 0.125f);
  }
  ((f16x2*)xk)[p] = v;
}

// ---------------------------------------------------------------- prepT (xkT, c-inner via LDS transpose)
// grid 984 = (kc*4+n)*82 + row; block 256; tile [c 128][w 64]
__global__ __launch_bounds__(256) void prepT_kernel(const float* __restrict__ x,
                                                    f16* __restrict__ xkT) {
  __shared__ float T[128][65];
  unsigned b   = blockIdx.x;
  unsigned row = b % 82u;
  unsigned t2_ = b / 82u;
  unsigned n   = t2_ & 3u;
  unsigned kc  = t2_ >> 2;
  int hsrc = (int)row - 9;
  unsigned tid = threadIdx.x;
  f16* oplane = xkT + (size_t)b * 8192u;

  if (hsrc >= 0 && hsrc < 64) {
    unsigned c = tid >> 1, half = (tid & 1u) * 32u;
    const float* src = x + ((size_t)(n * 128u + c) * 64u + (unsigned)hsrc) * 64u + half;
#pragma unroll
    for (int i = 0; i < 8; i++) {
      f32x4 v = *(const f32x4*)(src + i * 4);
      *(f32x4*)&T[c][half + (unsigned)i * 4u] = v;
    }
    __syncthreads();
    unsigned w = tid & 63u, c32 = (tid >> 6) * 32u;
    int wsrc = (int)w + 2 * (int)kc - 2;
    bool ok = (wsrc >= 0 && wsrc < 64);
#pragma unroll
    for (unsigned s = 0; s < 4u; s++) {
      f16x8 o;
#pragma unroll
      for (int i = 0; i < 8; i++)
        o[i] = ok ? (f16)(T[c32 + s * 8u + (unsigned)i][wsrc] * 0.125f) : (f16)0.f;
      *(f16x8*)(oplane + w * 128u + c32 + s * 8u) = o;
    }
  } else {
    f16x8 z = {};
#pragma unroll
    for (unsigned s = 0; s < 4u; s++)
      *(f16x8*)(oplane + (size_t)tid * 32u + s * 8u) = z;
  }
}

// ---------------------------------------------------------------- prepP (p5T, c-inner via LDS transpose)
// grid 1344 = rk*64 + h; block 256; tile [c 128][w 64]
__global__ __launch_bounds__(256) void prepP_kernel(const float* __restrict__ p5,
                                                    f16* __restrict__ p5T) {
  __shared__ float T[128][65];
  unsigned b  = blockIdx.x;
  unsigned h  = b & 63u;
  unsigned rk = b >> 6;
  unsigned tid = threadIdx.x;
  unsigned c = tid >> 1, half = (tid & 1u) * 32u;
  const float* src = p5 + ((size_t)c * 21u + rk) * 4096u + h * 64u + half;
#pragma unroll
  for (int i = 0; i < 8; i++) {
    f32x4 v = *(const f32x4*)(src + i * 4);
    *(f32x4*)&T[c][half + (unsigned)i * 4u] = v;
  }
  __syncthreads();
  unsigned w = tid & 63u, c32 = (tid >> 6) * 32u;
  f16* oplane = p5T + (size_t)b * 8192u;
#pragma unroll
  for (unsigned s = 0; s < 4u; s++) {
    f16x8 o;
#pragma unroll
    for (int i = 0; i < 8; i++)
      o[i] = (f16)T[c32 + s * 8u + (unsigned)i][w];
    *(f16x8*)(oplane + w * 128u + c32 + s * 8u) = o;
  }
}

// ---------------------------------------------------------------- gram (LDS-staged, split-K -> f16 partials)
__global__ __launch_bounds__(256, 3) void gram_kernel(const f16* __restrict__ xk,
                                                      f16* __restrict__ t3p) {
  __shared__ f16 gl[2 * 12288];

  unsigned b    = blockIdx.x;
  unsigned ks   = b & 7u;
  unsigned cseg = (b >> 3) & 1u;
  unsigned rk   = (b >> 4) % 21u;
  unsigned n    = b / (16u * 21u);
  unsigned r    = rk / 3u;
  unsigned kc   = rk - r * 3u;

  unsigned tid  = threadIdx.x;
  unsigned wv   = tid >> 6;
  unsigned lane = tid & 63u;
  unsigned wy   = wv >> 1;
  unsigned wx   = wv & 1u;
  unsigned quad = lane >> 4;
  unsigned l16  = lane & 15u;
  unsigned rsl  = lane >> 3;
  unsigned seg  = (lane & 7u) ^ (rsl & 7u);

  unsigned h0 = ks * 8u;
  const f16* Ab = xk + (size_t)(kc * 4u + n) * 128u * XSTR + (size_t)(cseg * 64u) * XSTR
                + (h0 + 3u * r) * 64u + seg * 8u;
  const f16* Bb = xk + (size_t)(4u + n) * 128u * XSTR + (h0 + 9u) * 64u + seg * 8u;
  unsigned ar0 = wv * 16u;
  unsigned br0 = wv * 32u;

  f32x4 acc[2][4] = {};

#pragma unroll
  for (unsigned t = 0; t < 2u; t++)
    gl16(Ab + (size_t)(ar0 + t * 8u + rsl) * XSTR, &gl[(ar0 + t * 8u) * 64u]);
#pragma unroll
  for (unsigned t = 0; t < 4u; t++)
    gl16(Bb + (size_t)(br0 + t * 8u + rsl) * XSTR, &gl[4096u + (br0 + t * 8u) * 64u]);

  for (unsigned s = 0; s < 8u; s++) {
    __syncthreads();
    if (s < 7u) {
      f16* base = &gl[((s + 1u) & 1u) * 12288u];
      unsigned off = (s + 1u) * 64u;
#pragma unroll
      for (unsigned t = 0; t < 2u; t++)
        gl16(Ab + off + (size_t)(ar0 + t * 8u + rsl) * XSTR, base + (ar0 + t * 8u) * 64u);
#pragma unroll
      for (unsigned t = 0; t < 4u; t++)
        gl16(Bb + off + (size_t)(br0 + t * 8u + rsl) * XSTR, base + 4096u + (br0 + t * 8u) * 64u);
    }
    const f16* bufA = &gl[(s & 1u) * 12288u];
    const f16* bufB = bufA + 4096u;
#pragma unroll
    for (unsigned t2 = 0; t2 < 2u; t2++) {
      unsigned L = t2 * 4u + quad;
      f16x8 a[2], bb[4];
#pragma unroll
      for (int ms = 0; ms < 2; ms++) {
        unsigned rr = wy * 32u + (unsigned)ms * 16u + l16;
        a[ms] = *(const f16x8*)&bufA[rr * 64u + (L ^ (rr & 7u)) * 8u];
      }
#pragma unroll
      for (int ns = 0; ns < 4; ns++) {
        unsigned rb = wx * 64u + (unsigned)ns * 16u + l16;
        bb[ns] = *(const f16x8*)&bufB[rb * 64u + (L ^ (rb & 7u)) * 8u];
      }
#pragma unroll
      for (int ms = 0; ms < 2; ms++)
#pragma unroll
        for (int ns = 0; ns < 4; ns++)
          acc[ms][ns] = __builtin_amdgcn_mfma_f32_16x16x32_f16(a[ms], bb[ns], acc[ms][ns], 0, 0, 0);
    }
  }

  f16* tp = t3p + ((size_t)(ks * 4u + n) * 21u + rk) * 16384u;
#pragma unroll
  for (int ms = 0; ms < 2; ms++) {
#pragma unroll
    for (int ns = 0; ns < 4; ns++) {
      unsigned c0 = cseg * 64u + wy * 32u + (unsigned)ms * 16u + quad * 4u;
      unsigned d  = wx * 64u + (unsigned)ns * 16u + l16;
#pragma unroll
      for (int reg = 0; reg < 4; reg++)
        tp[(size_t)(c0 + (unsigned)reg) * 128u + d] = (f16)acc[ms][ns][reg];
    }
  }
}

// ---------------------------------------------------------------- ep: t6T = p6 * sum_ks(t3p)
__global__ __launch_bounds__(256) void ep_kernel(const f16* __restrict__ t3p,
                                                 const float* __restrict__ p6,
                                                 f16* __restrict__ t6T) {
  unsigned idx = blockIdx.x * 256u + threadIdx.x;
  unsigned d4  = idx & 31u;
  unsigned c   = (idx >> 5) & 127u;
  unsigned t   = idx >> 12;
  unsigned rk  = t % 21u;
  unsigned n   = t / 21u;
  unsigned d0  = d4 * 4u;

  float s0 = 0.f, s1 = 0.f, s2 = 0.f, s3 = 0.f;
#pragma unroll
  for (unsigned ks = 0; ks < 8u; ks++) {
    f16x4 v = *(const f16x4*)(t3p + (((size_t)(ks * 4u + n) * 21u + rk) * 16384u + c * 128u + d0));
    s0 += (float)v[0]; s1 += (float)v[1]; s2 += (float)v[2]; s3 += (float)v[3];
  }
  const float* pp = p6 + ((size_t)c * 21u + rk) * 128u + d0;
  f16 o0 = (f16)(s0 * pp[0]);
  f16 o1 = (f16)(s1 * pp[1]);
  f16 o2 = (f16)(s2 * pp[2]);
  f16 o3 = (f16)(s3 * pp[3]);
  f16* ob = t6T + (size_t)(n * 128u + d0) * 2688u + rk * 128u + c;
  ob[0] = o0; ob[2688] = o1; ob[2 * 2688] = o2; ob[3 * 2688] = o3;
}

// ---------------------------------------------------------------- outp (t8 split-K x4, barrier-free loop)
// grid 1024 = n(4)*h(64)*g(4); block 256 (4 waves 2x2), tile 64w x 128d.
// A-fragments DIRECT from c-inner xkT/p5T (f16x8), modulation = packed f16 fma in regs.
#define RT_STR 66
__global__ __launch_bounds__(256, 4) void outp_kernel(const f16* __restrict__ xkT,
                                                      const f16* __restrict__ p5T,
                                                      const f16* __restrict__ t6T,
                                                      f16* __restrict__ t8p) {
  __shared__ float Rt[128 * RT_STR];   // epilogue transpose only

  unsigned b = blockIdx.x;
  unsigned g = b & 3u;
  unsigned h = (b >> 2) & 63u;
  unsigned n = b >> 8;

  unsigned tid  = threadIdx.x;
  unsigned wv   = tid >> 6;
  unsigned lane = tid & 63u;
  unsigned wy   = wv >> 1;
  unsigned wx   = wv & 1u;
  unsigned quad = lane >> 4;
  unsigned l16  = lane & 15u;

  unsigned koff  = g * 32u + quad * 8u;
  unsigned wbase = (wy * 32u + l16) * 128u + koff;        // ms=0 A offset within plane
  const f16* xbase = xkT + (size_t)(n * 82u) * 8192u + wbase;   // + (kc*4*82 + 3r)*8192 via plane idx
  const f16* pbase = p5T + (size_t)h * 8192u + wbase;
  const f16* bfb   = t6T + (size_t)(n * 128u + wx * 64u + l16) * 2688u + koff;

  f32x4 acc[2][4] = {};

#pragma unroll
  for (unsigned j = 0; j < 21u; j++) {
    unsigned r  = j / 3u;
    unsigned kc = j % 3u;
    const f16* xp = xbase + (size_t)(kc * 4u * 82u + h + 3u * r) * 8192u;
    const f16* pp = pbase + (size_t)j * 64u * 8192u;
    f16x8 xa0 = *(const f16x8*)(xp);
    f16x8 xa1 = *(const f16x8*)(xp + 16u * 128u);
    f16x8 pa0 = *(const f16x8*)(pp);
    f16x8 pa1 = *(const f16x8*)(pp + 16u * 128u);
    f16x8 bf[4];
#pragma unroll
    for (int ns = 0; ns < 4; ns++)
      bf[ns] = *(const f16x8*)(bfb + (size_t)ns * 16u * 2688u + j * 128u);
    f16x8 av0 = xa0 * pa0 + xa0;   // v_pk_fma_f16 x4
    f16x8 av1 = xa1 * pa1 + xa1;
#pragma unroll
    for (int ns = 0; ns < 4; ns++) {
      acc[0][ns] = __builtin_amdgcn_mfma_f32_16x16x32_f16(av0, bf[ns], acc[0][ns], 0, 0, 0);
      acc[1][ns] = __builtin_amdgcn_mfma_f32_16x16x32_f16(av1, bf[ns], acc[1][ns], 0, 0, 0);
    }
  }

  // transpose via LDS for coalesced f16 partial stores: t8p[g][n][h][d][w]
#pragma unroll
  for (int ms = 0; ms < 2; ms++)
#pragma unroll
    for (int ns = 0; ns < 4; ns++) {
      unsigned w0 = wy * 32u + (unsigned)ms * 16u + quad * 4u;
      unsigned d  = wx * 64u + (unsigned)ns * 16u + l16;
#pragma unroll
      for (int reg = 0; reg < 4; reg++)
        Rt[d * RT_STR + w0 + (unsigned)reg] = acc[ms][ns][reg];
    }
  __syncthreads();
  f16* op = t8p + ((size_t)((g * 4u + n) * 64u + h)) * 8192u;
#pragma unroll
  for (unsigned it = 0; it < 4u; it++) {
    unsigned row = (tid >> 3) + it * 32u;
    unsigned w0  = (tid & 7u) * 8u;
    f16x8 o;
#pragma unroll
    for (int i = 0; i < 8; i++) o[i] = (f16)Rt[row * RT_STR + w0 + (unsigned)i];
    *(f16x8*)(op + row * 64u + w0) = o;
  }
}

// ---------------------------------------------------------------- red: out = FS * sum_g(t8p)
__global__ __launch_bounds__(256) void red_kernel(const f16* __restrict__ t8p,
                                                  float* __restrict__ out) {
  unsigned idx = blockIdx.x * 256u + threadIdx.x;
  unsigned w0 = (idx & 7u) * 8u;
  unsigned h  = (idx >> 3) & 63u;
  unsigned d  = (idx >> 9) & 127u;
  unsigned n  = idx >> 16;
  const float FS = 0.15430334996209192f;  // 8 / sqrt(2688)
  float s[8] = {};
#pragma unroll
  for (unsigned g = 0; g < 4u; g++) {
    f16x8 v = *(const f16x8*)(t8p + ((size_t)((g * 4u + n) * 64u + h)) * 8192u + d * 64u + w0);
#pragma unroll
    for (int i = 0; i < 8; i++) s[i] += (float)v[i];
  }
  f32x4 o0, o1;
#pragma unroll
  for (int i = 0; i < 4; i++) { o0[i] = s[i] * FS; o1[i] = s[i + 4] * FS; }
  float* op = out + ((size_t)(n * 128u + d) * 64u + h) * 64u + w0;
  *(f32x4*)op = o0;
  *(f32x4*)(op + 4) = o1;
}

// ---------------------------------------------------------------- launch
extern "C" void kernel_launch(void* const* d_in, const int* in_sizes, int n_in,
                              void* d_out, int out_size, void* d_ws, size_t ws_size,
                              hipStream_t stream) {
  const float* x  = (const float*)d_in[0];
  const float* p5 = (const float*)d_in[1];
  const float* p6 = (const float*)d_in[2];
  float* out = (float*)d_out;
  f16* xk  = (f16*)((char*)d_ws);
  f16* xkT = (f16*)((char*)d_ws + XKT_OFF);
  f16* p5T = (f16*)((char*)d_ws + P5T_OFF);
  f16* t6T = (f16*)((char*)d_ws + T6T_OFF);
  f16* t3p = (f16*)((char*)d_ws + T3P_OFF);
  f16* t8p = (f16*)((char*)d_ws + T8P_OFF);   // aliases t3p (t3p dead by then)

  unsigned prep_blocks = (3u * 4u * 128u * 82u * 32u + 255u) / 256u;  // 15744
  hipLaunchKernelGGL(prep_kernel,  dim3(prep_blocks), dim3(256), 0, stream, x, xk);
  hipLaunchKernelGGL(prepT_kernel, dim3(984),  dim3(256), 0, stream, x, xkT);
  hipLaunchKernelGGL(prepP_kernel, dim3(1344), dim3(256), 0, stream, p5, p5T);
  hipLaunchKernelGGL(gram_kernel,  dim3(1344), dim3(256), 0, stream, xk, t3p);
  hipLaunchKernelGGL(ep_kernel,    dim3(1344), dim3(256), 0, stream, t3p, p6, t6T);
  hipLaunchKernelGGL(outp_kernel,  dim3(1024), dim3(256), 0, stream, xkT, p5T, t6T, t8p);
  hipLaunchKernelGGL(red_kernel,   dim3(1024), dim3(256), 0, stream, t8p, out);
}

// Round 6
// 213.142 us; speedup vs baseline: 1.0475x; 1.0475x over previous
//
#include <hip/hip_runtime.h>

typedef _Float16 f16;
typedef _Float16 f16x2 __attribute__((ext_vector_type(2)));
typedef _Float16 f16x4 __attribute__((ext_vector_type(4)));
typedef _Float16 f16x8 __attribute__((ext_vector_type(8)));
typedef float    f32x4 __attribute__((ext_vector_type(4)));

// Geometry:
//   x:   (4,128,64,64) f32     p5: (128,21,64,64) f32
//   p6:  (128,21,128)  f32     out:(4,128,64,64)  f32
// Workspace:
//   xk   [3][4][128][82][64] f16      = x*(1/8), w-inner (gram operands)
//   xkTg [4g][3][4][82][64][32] f16   = x*(1/8), g-major c32-inner (outp A)
//   p5Tg [4g][21][64][64][32] f16     = p5, g-major c32-inner
//   t6T  [4][128][2688] f16           = p6 * t3, d-major
//   t3p  [8][4][21][128][128] f16     = split-K Gram partials (aliased by t8p)
//   t8p  [4][4][64][128][64] f16      = split-K out partials
#define XROWS 82
#define XSTR  (XROWS * 64)
#define XK_ELEMS  (3u * 4u * 128u * (unsigned)XSTR)
static const size_t XKT_OFF   = (size_t)XK_ELEMS * 2;                 // 16.12 MB
static const size_t XKT_BYTES = (size_t)4 * 3 * 4 * 82 * 64 * 32 * 2; // 16.12 MB
static const size_t P5T_OFF   = XKT_OFF + XKT_BYTES;
static const size_t P5T_BYTES = (size_t)4 * 21 * 64 * 64 * 32 * 2;    // 22.0 MB
static const size_t T6T_OFF   = P5T_OFF + P5T_BYTES;
static const size_t T6T_BYTES = (size_t)4 * 128 * 2688 * 2;           // 2.75 MB
static const size_t T3P_OFF   = T6T_OFF + T6T_BYTES;
static const size_t T8P_OFF   = T3P_OFF;   // t3p dead before outp writes t8p

__device__ __forceinline__ void gl16(const f16* g, f16* l) {
  __builtin_amdgcn_global_load_lds((const __attribute__((address_space(1))) void*)g,
                                   (__attribute__((address_space(3))) void*)l, 16, 0, 0);
}

// ---------------------------------------------------------------- prep (xk, w-inner)
__global__ __launch_bounds__(256) void prep_kernel(const float* __restrict__ x,
                                                   f16* __restrict__ xk) {
  unsigned p = blockIdx.x * 256u + threadIdx.x;
  unsigned total = 3u * 4u * 128u * 82u * 32u;
  if (p >= total) return;
  unsigned wp   = p & 31u;
  unsigned row  = (p >> 5) % 82u;
  unsigned rest = p / (32u * 82u);
  unsigned c    = rest & 127u;
  unsigned rest2 = rest >> 7;
  unsigned n    = rest2 & 3u;
  unsigned kc   = rest2 >> 2;
  int hsrc = (int)row - 9;
  int wsrc = (int)(wp * 2u) + 2 * (int)kc - 2;
  f16x2 v; v.x = (f16)0.f; v.y = (f16)0.f;
  if (hsrc >= 0 && hsrc < 64 && wsrc >= 0 && wsrc < 64) {
    const float2* src = (const float2*)(x + (((size_t)(n * 128u + c) * 64u + (unsigned)hsrc) * 64u + (unsigned)wsrc));
    float2 xv = *src;
    v.x = (f16)(xv.x * 0.125f);
    v.y = (f16)(xv.y * 0.125f);
  }
  ((f16x2*)xk)[p] = v;
}

// ---------------------------------------------------------------- prepT (xkTg, g-major c32-inner)
// grid 984 = (kc*4+n)*82 + row; block 256
__global__ __launch_bounds__(256) void prepT_kernel(const float* __restrict__ x,
                                                    f16* __restrict__ xkT) {
  __shared__ float T[128][65];
  unsigned b   = blockIdx.x;
  unsigned row = b % 82u;
  unsigned t2_ = b / 82u;
  unsigned n   = t2_ & 3u;
  unsigned kc  = t2_ >> 2;
  int hsrc = (int)row - 9;
  unsigned tid = threadIdx.x;
  unsigned w = tid & 63u, g = tid >> 6;
  f16* oplane = xkT + (((size_t)(g * 3u + kc) * 4u + n) * 82u + row) * 2048u;

  if (hsrc >= 0 && hsrc < 64) {
    unsigned c = tid >> 1, half = (tid & 1u) * 32u;
    const float* src = x + ((size_t)(n * 128u + c) * 64u + (unsigned)hsrc) * 64u + half;
#pragma unroll
    for (int i = 0; i < 8; i++) {
      f32x4 v = *(const f32x4*)(src + i * 4);
      *(f32x4*)&T[c][half + (unsigned)i * 4u] = v;
    }
    __syncthreads();
    int wsrc = (int)w + 2 * (int)kc - 2;
    bool ok = (wsrc >= 0 && wsrc < 64);
#pragma unroll
    for (unsigned s = 0; s < 4u; s++) {
      f16x8 o;
#pragma unroll
      for (int i = 0; i < 8; i++)
        o[i] = ok ? (f16)(T[g * 32u + s * 8u + (unsigned)i][wsrc] * 0.125f) : (f16)0.f;
      *(f16x8*)(oplane + w * 32u + s * 8u) = o;
    }
  } else {
    f16x8 z = {};
#pragma unroll
    for (unsigned s = 0; s < 4u; s++)
      *(f16x8*)(oplane + w * 32u + s * 8u) = z;
  }
}

// ---------------------------------------------------------------- prepP (p5Tg, g-major c32-inner)
// grid 1344 = rk*64 + h; block 256
__global__ __launch_bounds__(256) void prepP_kernel(const float* __restrict__ p5,
                                                    f16* __restrict__ p5T) {
  __shared__ float T[128][65];
  unsigned b  = blockIdx.x;
  unsigned h  = b & 63u;
  unsigned rk = b >> 6;
  unsigned tid = threadIdx.x;
  unsigned c = tid >> 1, half = (tid & 1u) * 32u;
  const float* src = p5 + ((size_t)c * 21u + rk) * 4096u + h * 64u + half;
#pragma unroll
  for (int i = 0; i < 8; i++) {
    f32x4 v = *(const f32x4*)(src + i * 4);
    *(f32x4*)&T[c][half + (unsigned)i * 4u] = v;
  }
  __syncthreads();
  unsigned w = tid & 63u, g = tid >> 6;
  f16* oplane = p5T + (((size_t)(g * 21u + rk) * 64u + h)) * 2048u;
#pragma unroll
  for (unsigned s = 0; s < 4u; s++) {
    f16x8 o;
#pragma unroll
    for (int i = 0; i < 8; i++)
      o[i] = (f16)T[g * 32u + s * 8u + (unsigned)i][w];
    *(f16x8*)(oplane + w * 32u + s * 8u) = o;
  }
}

// ---------------------------------------------------------------- gram v4 (one-shot staged halves)
// grid 672 = n(4)*rk(21)*ks(8); block 256 (4 waves 2x2, each 64c x 64d), tile 128c x 128d.
// K-slice 512 (8 h rows) in 2 halves of 256; per half: burst-stage A+B (128 KB LDS,
// XOR-swizzled 16B chunks), ONE drain, 8 sub-steps x 16 MFMA.
__global__ __launch_bounds__(256, 1) void gram_kernel(const f16* __restrict__ xk,
                                                      f16* __restrict__ t3p) {
  __shared__ f16 gl[2 * 128 * 256];   // A 64 KB + B 64 KB

  unsigned b  = blockIdx.x;
  unsigned ks = b & 7u;
  unsigned rk = (b >> 3) % 21u;
  unsigned n  = b / (8u * 21u);
  unsigned r  = rk / 3u;
  unsigned kc = rk - r * 3u;

  unsigned tid  = threadIdx.x;
  unsigned wv   = tid >> 6;
  unsigned lane = tid & 63u;
  unsigned wy   = wv >> 1;
  unsigned wx   = wv & 1u;
  unsigned quad = lane >> 4;
  unsigned l16  = lane & 15u;
  unsigned lrow   = lane >> 5;     // row within staged pair
  unsigned lchunk = lane & 31u;    // dest 16B chunk within row

  unsigned h0 = ks * 8u;
  const f16* Ag = xk + (size_t)(kc * 4u + n) * 128u * XSTR + (h0 + 3u * r) * 64u;
  const f16* Bg = xk + (size_t)(4u + n) * 128u * XSTR + (h0 + 9u) * 64u;

  f32x4 acc[4][4] = {};

  for (unsigned hh = 0; hh < 2u; hh++) {
    if (hh) __syncthreads();           // all reads of half 0 done before overwrite
    unsigned srcoff = hh * 256u;
    // stage A then B: 16+16 gl16 per wave; dest base wave-uniform, 2 rows/instr
#pragma unroll
    for (unsigned i = 0; i < 16u; i++) {
      unsigned r0  = wv * 32u + i * 2u;
      unsigned row = r0 + lrow;
      unsigned co  = (lchunk ^ (row & 7u)) * 8u;
      gl16(Ag + (size_t)row * XSTR + srcoff + co, &gl[r0 * 256u]);
    }
#pragma unroll
    for (unsigned i = 0; i < 16u; i++) {
      unsigned r0  = wv * 32u + i * 2u;
      unsigned row = r0 + lrow;
      unsigned co  = (lchunk ^ (row & 7u)) * 8u;
      gl16(Bg + (size_t)row * XSTR + srcoff + co, &gl[32768u + r0 * 256u]);
    }
    __syncthreads();                   // single vmcnt drain per half

#pragma unroll
    for (unsigned t = 0; t < 8u; t++) {
      f16x8 af[4], bf[4];
#pragma unroll
      for (int ms = 0; ms < 4; ms++) {
        unsigned rr = wy * 64u + (unsigned)ms * 16u + l16;
        af[ms] = *(const f16x8*)&gl[rr * 256u + ((t * 4u + quad) ^ (rr & 7u)) * 8u];
      }
#pragma unroll
      for (int ns = 0; ns < 4; ns++) {
        unsigned rb = wx * 64u + (unsigned)ns * 16u + l16;
        bf[ns] = *(const f16x8*)&gl[32768u + rb * 256u + ((t * 4u + quad) ^ (rb & 7u)) * 8u];
      }
#pragma unroll
      for (int ms = 0; ms < 4; ms++)
#pragma unroll
        for (int ns = 0; ns < 4; ns++)
          acc[ms][ns] = __builtin_amdgcn_mfma_f32_16x16x32_f16(af[ms], bf[ns], acc[ms][ns], 0, 0, 0);
    }
  }

  // f16 partial store: t3p[ks][n][rk][c][d]
  f16* tp = t3p + ((size_t)(ks * 4u + n) * 21u + rk) * 16384u;
#pragma unroll
  for (int ms = 0; ms < 4; ms++) {
#pragma unroll
    for (int ns = 0; ns < 4; ns++) {
      unsigned c0 = wy * 64u + (unsigned)ms * 16u + quad * 4u;
      unsigned d  = wx * 64u + (unsigned)ns * 16u + l16;
#pragma unroll
      for (int reg = 0; reg < 4; reg++)
        tp[(size_t)(c0 + (unsigned)reg) * 128u + d] = (f16)acc[ms][ns][reg];
    }
  }
}

// ---------------------------------------------------------------- ep: t6T = p6 * sum_ks(t3p)
__global__ __launch_bounds__(256) void ep_kernel(const f16* __restrict__ t3p,
                                                 const float* __restrict__ p6,
                                                 f16* __restrict__ t6T) {
  unsigned idx = blockIdx.x * 256u + threadIdx.x;
  unsigned d4  = idx & 31u;
  unsigned c   = (idx >> 5) & 127u;
  unsigned t   = idx >> 12;
  unsigned rk  = t % 21u;
  unsigned n   = t / 21u;
  unsigned d0  = d4 * 4u;

  float s0 = 0.f, s1 = 0.f, s2 = 0.f, s3 = 0.f;
#pragma unroll
  for (unsigned ks = 0; ks < 8u; ks++) {
    f16x4 v = *(const f16x4*)(t3p + (((size_t)(ks * 4u + n) * 21u + rk) * 16384u + c * 128u + d0));
    s0 += (float)v[0]; s1 += (float)v[1]; s2 += (float)v[2]; s3 += (float)v[3];
  }
  const float* pp = p6 + ((size_t)c * 21u + rk) * 128u + d0;
  f16 o0 = (f16)(s0 * pp[0]);
  f16 o1 = (f16)(s1 * pp[1]);
  f16 o2 = (f16)(s2 * pp[2]);
  f16 o3 = (f16)(s3 * pp[3]);
  f16* ob = t6T + (size_t)(n * 128u + d0) * 2688u + rk * 128u + c;
  ob[0] = o0; ob[2688] = o1; ob[2 * 2688] = o2; ob[3 * 2688] = o3;
}

// ---------------------------------------------------------------- outp (t8 split-K x4, barrier-free loop)
// grid 1024 = n(4)*h(64)*g(4); block 256 (4 waves 2x2), tile 64w x 128d.
// A-fragments from g-major c32-inner layouts: every wave load = 1 KB fully-consumed contiguous.
#define RT_STR 66
__global__ __launch_bounds__(256, 4) void outp_kernel(const f16* __restrict__ xkT,
                                                      const f16* __restrict__ p5T,
                                                      const f16* __restrict__ t6T,
                                                      f16* __restrict__ t8p) {
  __shared__ float Rt[128 * RT_STR];   // epilogue transpose only

  unsigned b = blockIdx.x;
  unsigned g = b & 3u;
  unsigned h = (b >> 2) & 63u;
  unsigned n = b >> 8;

  unsigned tid  = threadIdx.x;
  unsigned wv   = tid >> 6;
  unsigned lane = tid & 63u;
  unsigned wy   = wv >> 1;
  unsigned wx   = wv & 1u;
  unsigned quad = lane >> 4;
  unsigned l16  = lane & 15u;

  unsigned awoff = (wy * 32u + l16) * 32u + quad * 8u;   // ms=0; ms=1: +512
  const f16* xnb = xkT + ((size_t)(g * 3u) * 4u + n) * 82u * 2048u;   // + (kc*4*82... via plane idx
  const f16* pgb = p5T + (size_t)g * 21u * 64u * 2048u + (size_t)h * 2048u;
  const f16* bfb = t6T + (size_t)(n * 128u + wx * 64u + l16) * 2688u + g * 32u + quad * 8u;

  f32x4 acc[2][4] = {};

#pragma unroll
  for (unsigned j = 0; j < 21u; j++) {
    unsigned r  = j / 3u;
    unsigned kc = j % 3u;
    const f16* xp = xnb + ((size_t)(kc * 4u * 82u) + h + 3u * r) * 2048u + awoff;
    const f16* pp = pgb + (size_t)j * 64u * 2048u + awoff;
    f16x8 xa0 = *(const f16x8*)(xp);
    f16x8 xa1 = *(const f16x8*)(xp + 512u);
    f16x8 pa0 = *(const f16x8*)(pp);
    f16x8 pa1 = *(const f16x8*)(pp + 512u);
    f16x8 bf[4];
#pragma unroll
    for (int ns = 0; ns < 4; ns++)
      bf[ns] = *(const f16x8*)(bfb + (size_t)ns * 16u * 2688u + j * 128u);
    f16x8 av0 = xa0 * pa0 + xa0;   // packed f16 fma
    f16x8 av1 = xa1 * pa1 + xa1;
#pragma unroll
    for (int ns = 0; ns < 4; ns++) {
      acc[0][ns] = __builtin_amdgcn_mfma_f32_16x16x32_f16(av0, bf[ns], acc[0][ns], 0, 0, 0);
      acc[1][ns] = __builtin_amdgcn_mfma_f32_16x16x32_f16(av1, bf[ns], acc[1][ns], 0, 0, 0);
    }
  }

  // transpose via LDS for coalesced f16 partial stores: t8p[g][n][h][d][w]
#pragma unroll
  for (int ms = 0; ms < 2; ms++)
#pragma unroll
    for (int ns = 0; ns < 4; ns++) {
      unsigned w0 = wy * 32u + (unsigned)ms * 16u + quad * 4u;
      unsigned d  = wx * 64u + (unsigned)ns * 16u + l16;
#pragma unroll
      for (int reg = 0; reg < 4; reg++)
        Rt[d * RT_STR + w0 + (unsigned)reg] = acc[ms][ns][reg];
    }
  __syncthreads();
  f16* op = t8p + ((size_t)((g * 4u + n) * 64u + h)) * 8192u;
#pragma unroll
  for (unsigned it = 0; it < 4u; it++) {
    unsigned row = (tid >> 3) + it * 32u;
    unsigned w0  = (tid & 7u) * 8u;
    f16x8 o;
#pragma unroll
    for (int i = 0; i < 8; i++) o[i] = (f16)Rt[row * RT_STR + w0 + (unsigned)i];
    *(f16x8*)(op + row * 64u + w0) = o;
  }
}

// ---------------------------------------------------------------- red: out = FS * sum_g(t8p)
__global__ __launch_bounds__(256) void red_kernel(const f16* __restrict__ t8p,
                                                  float* __restrict__ out) {
  unsigned idx = blockIdx.x * 256u + threadIdx.x;
  unsigned w0 = (idx & 7u) * 8u;
  unsigned h  = (idx >> 3) & 63u;
  unsigned d  = (idx >> 9) & 127u;
  unsigned n  = idx >> 16;
  const float FS = 0.15430334996209192f;  // 8 / sqrt(2688)
  float s[8] = {};
#pragma unroll
  for (unsigned g = 0; g < 4u; g++) {
    f16x8 v = *(const f16x8*)(t8p + ((size_t)((g * 4u + n) * 64u + h)) * 8192u + d * 64u + w0);
#pragma unroll
    for (int i = 0; i < 8; i++) s[i] += (float)v[i];
  }
  f32x4 o0, o1;
#pragma unroll
  for (int i = 0; i < 4; i++) { o0[i] = s[i] * FS; o1[i] = s[i + 4] * FS; }
  float* op = out + ((size_t)(n * 128u + d) * 64u + h) * 64u + w0;
  *(f32x4*)op = o0;
  *(f32x4*)(op + 4) = o1;
}

// ---------------------------------------------------------------- launch
extern "C" void kernel_launch(void* const* d_in, const int* in_sizes, int n_in,
                              void* d_out, int out_size, void* d_ws, size_t ws_size,
                              hipStream_t stream) {
  const float* x  = (const float*)d_in[0];
  const float* p5 = (const float*)d_in[1];
  const float* p6 = (const float*)d_in[2];
  float* out = (float*)d_out;
  f16* xk  = (f16*)((char*)d_ws);
  f16* xkT = (f16*)((char*)d_ws + XKT_OFF);
  f16* p5T = (f16*)((char*)d_ws + P5T_OFF);
  f16* t6T = (f16*)((char*)d_ws + T6T_OFF);
  f16* t3p = (f16*)((char*)d_ws + T3P_OFF);
  f16* t8p = (f16*)((char*)d_ws + T8P_OFF);   // aliases t3p (t3p dead by then)

  unsigned prep_blocks = (3u * 4u * 128u * 82u * 32u + 255u) / 256u;  // 15744
  hipLaunchKernelGGL(prep_kernel,  dim3(prep_blocks), dim3(256), 0, stream, x, xk);
  hipLaunchKernelGGL(prepT_kernel, dim3(984),  dim3(256), 0, stream, x, xkT);
  hipLaunchKernelGGL(prepP_kernel, dim3(1344), dim3(256), 0, stream, p5, p5T);
  hipLaunchKernelGGL(gram_kernel,  dim3(672),  dim3(256), 0, stream, xk, t3p);
  hipLaunchKernelGGL(ep_kernel,    dim3(1344), dim3(256), 0, stream, t3p, p6, t6T);
  hipLaunchKernelGGL(outp_kernel,  dim3(1024), dim3(256), 0, stream, xkT, p5T, t6T, t8p);
  hipLaunchKernelGGL(red_kernel,   dim3(1024), dim3(256), 0, stream, t8p, out);
}